// Round 2
// baseline (489.659 us; speedup 1.0000x reference)
//
#include <hip/hip_runtime.h>
#include <hip/hip_fp16.h>
#include <cstdint>
#include <cmath>

#define TOKENS  16384
#define HIDDEN  4096
#define NEXP    256
#define TOPK    8
#define KDROP   4   /* n_group - topk_group */

typedef _Float16 f16x8  __attribute__((ext_vector_type(8)));
typedef _Float16 f16x4  __attribute__((ext_vector_type(4)));
typedef float    f32x16 __attribute__((ext_vector_type(16)));
typedef float    f32x4  __attribute__((ext_vector_type(4)));

#define LO_SCALE 2048.0f          /* 2^11 */
#define LO_INV   (1.0f/2048.0f)

// ws layout (bytes):
//   [0, 2097152)             w_h  f16 chunk-array
//   [2097152, +2097152)      w_l  f16 chunk-array (scaled by 2^11)
#define WS_WH_OFF 0
#define WS_WL_OFF 2097152

// non-temporal loads: x / w are strictly streaming (zero reuse in L2 terms)
static __device__ __forceinline__ f32x4 ldnt4(const float* p) {
    return __builtin_nontemporal_load((const f32x4*)p);
}

// ---------------------------------------------------------------------------
// Pre-kernel: split w (fp32) into f16 hi / (lo*2^11) stored in MFMA-frag
// chunk order: chunk (e,k8grp) -> cid = ((kc*2+s)*8 + e/32)*64 + hl*32 + e%32
// where kc=k/32, s=(k/16)%2, hl=(k/8)%2.  Each chunk = 8 consecutive k f16.
// ---------------------------------------------------------------------------
__global__ __launch_bounds__(256)
void wsplit(const float* __restrict__ w, _Float16* __restrict__ wh,
            _Float16* __restrict__ wl)
{
    const int idx = blockIdx.x * 256 + threadIdx.x;   // 0..131071
    const int e   = idx >> 9;                         // expert 0..255
    const int kg8 = idx & 511;                        // 8-k group
    const float* p = w + (size_t)e * HIDDEN + kg8 * 8;
    f32x4 f0 = ldnt4(p);
    f32x4 f1 = ldnt4(p + 4);
    float v[8] = {f0.x, f0.y, f0.z, f0.w, f1.x, f1.y, f1.z, f1.w};
    f16x8 hi, lo;
    #pragma unroll
    for (int i = 0; i < 8; ++i) {
        _Float16 h = (_Float16)v[i];
        hi[i] = h;
        lo[i] = (_Float16)((v[i] - (float)h) * LO_SCALE);
    }
    const int kc = kg8 >> 2, s = (kg8 >> 1) & 1, hl = kg8 & 1;
    const int cid = ((kc * 2 + s) * 8 + (e >> 5)) * 64 + hl * 32 + (e & 31);
    ((f16x8*)wh)[cid] = hi;
    ((f16x8*)wl)[cid] = lo;
}

__device__ __forceinline__ unsigned ordkey(float f) {
    unsigned u = __float_as_uint(f);
    return (u & 0x80000000u) ? ~u : (u | 0x80000000u);  // monotone float->uint
}

// ---------------------------------------------------------------------------
// Fused GEMM + gating: one block = 32 tokens x 256 experts, FULL K (no split).
// 512 blocks x 256 threads, 2 blocks/CU (2 waves/SIMD).
// Wave wv: experts [wv*64, wv*64+64), 1x2 MFMA tiles of 32x32.
// A double-buffered in LDS (one barrier/iter); B register-prefetched one
// iteration ahead from the chunk-ordered, L2-resident wh/wl.
// After the K loop: sigmoid -> LDS (32x256 f32, 32 KB), barrier, in-block
// per-wave top-k (8 tokens/wave) -- gates never touch HBM.
// ---------------------------------------------------------------------------
__global__ __launch_bounds__(256, 2)
void gemm_gate(const float* __restrict__ x, const _Float16* __restrict__ wh,
               const _Float16* __restrict__ wl,
               const float* __restrict__ bias, float* __restrict__ out)
{
    __shared__ _Float16 Ah[2][32 * 32];   // 2 x 2 KB, chunk-array order
    __shared__ _Float16 Al[2][32 * 32];   // 2 x 2 KB
    __shared__ float sigbuf[32 * 256];    // 32 KB

    const int tid  = threadIdx.x;
    const int wv   = tid >> 6;
    const int lane = tid & 63;
    const int tok0 = blockIdx.x * 32;

    // A staging: thread t loads 4 consecutive k of one token row
    const int sm = tid >> 3;            // local token 0..31
    const int sq = tid & 7;             // 4-k group within the 32-k chunk
    const float* xr = x + (size_t)(tok0 + sm) * HIDDEN + sq * 4;
    // f16 store index: chunk = s*64 + hl*32 + sm, elem offset (sq&1)*4
    const int sidx = ((sq >> 2) * 64 + ((sq >> 1) & 1) * 32 + sm) * 8 + (sq & 1) * 4;

    const f16x8* whc = (const f16x8*)wh;
    const f16x8* wlc = (const f16x8*)wl;

    f32x16 accH[2] = {};   // hi*hi               [ntile c]
    f32x16 accX[2] = {};   // lo*hi + hi*lo (x 2^11)

    f16x8 bh[2][2], bl[2][2];   // current iteration's B frags [kstep s][ntile c]

    // ---- prologue: A(0) -> LDS[0], B(0) -> regs
    {
        f32x4 a = ldnt4(xr);
        #pragma unroll
        for (int s = 0; s < 2; ++s) {
            const int base = (s * 8 + wv * 2) * 64 + lane;
            bh[s][0] = whc[base];
            bh[s][1] = whc[base + 64];
            bl[s][0] = wlc[base];
            bl[s][1] = wlc[base + 64];
        }
        f16x4 hi, lo;
        #pragma unroll
        for (int i = 0; i < 4; ++i) {
            _Float16 h = (_Float16)a[i];
            hi[i] = h;
            lo[i] = (_Float16)((a[i] - (float)h) * LO_SCALE);
        }
        *(f16x4*)&Ah[0][sidx] = hi;
        *(f16x4*)&Al[0][sidx] = lo;
    }
    __syncthreads();

    #pragma unroll 2
    for (int kc = 0; kc < 128; ++kc) {
        const int cur  = kc & 1;
        const bool more = (kc < 127);

        // ---- prefetch next iteration (A raw + B frags) into registers
        f32x4 an;
        f16x8 bhn[2][2], bln[2][2];
        if (more) {
            an = ldnt4(xr + (kc + 1) * 32);
            #pragma unroll
            for (int s = 0; s < 2; ++s) {
                const int base = (((kc + 1) * 2 + s) * 8 + wv * 2) * 64 + lane;
                bhn[s][0] = whc[base];
                bhn[s][1] = whc[base + 64];
                bln[s][0] = wlc[base];
                bln[s][1] = wlc[base + 64];
            }
        }

        // ---- compute on LDS[cur] with current B regs (loaded last iter)
        #pragma unroll
        for (int s = 0; s < 2; ++s) {
            f16x8 ah = *(const f16x8*)&Ah[cur][(s * 64 + lane) * 8];
            f16x8 al = *(const f16x8*)&Al[cur][(s * 64 + lane) * 8];

            accH[0] = __builtin_amdgcn_mfma_f32_32x32x16_f16(ah, bh[s][0], accH[0], 0, 0, 0);
            accH[1] = __builtin_amdgcn_mfma_f32_32x32x16_f16(ah, bh[s][1], accH[1], 0, 0, 0);
            accX[0] = __builtin_amdgcn_mfma_f32_32x32x16_f16(al, bh[s][0], accX[0], 0, 0, 0);
            accX[1] = __builtin_amdgcn_mfma_f32_32x32x16_f16(al, bh[s][1], accX[1], 0, 0, 0);
            accX[0] = __builtin_amdgcn_mfma_f32_32x32x16_f16(ah, bl[s][0], accX[0], 0, 0, 0);
            accX[1] = __builtin_amdgcn_mfma_f32_32x32x16_f16(ah, bl[s][1], accX[1], 0, 0, 0);
        }

        // ---- store next A tile into the other LDS buffer; rotate B regs
        if (more) {
            f16x4 hi, lo;
            #pragma unroll
            for (int i = 0; i < 4; ++i) {
                _Float16 h = (_Float16)an[i];
                hi[i] = h;
                lo[i] = (_Float16)((an[i] - (float)h) * LO_SCALE);
            }
            *(f16x4*)&Ah[cur ^ 1][sidx] = hi;
            *(f16x4*)&Al[cur ^ 1][sidx] = lo;
            #pragma unroll
            for (int s = 0; s < 2; ++s) {
                bh[s][0] = bhn[s][0]; bh[s][1] = bhn[s][1];
                bl[s][0] = bln[s][0]; bl[s][1] = bln[s][1];
            }
        }
        __syncthreads();
    }

    // ---- combine hi + lo*2^-11, sigmoid, drop into LDS (no HBM round-trip)
    {
        const int col   = lane & 31;
        const int rbase = 4 * (lane >> 5);
        #pragma unroll
        for (int c = 0; c < 2; ++c) {
            #pragma unroll
            for (int reg = 0; reg < 16; ++reg) {
                const int row = (reg & 3) + 8 * (reg >> 2) + rbase;   // token 0..31
                const float g = accH[c][reg] + accX[c][reg] * LO_INV;
                sigbuf[row * NEXP + wv * 64 + c * 32 + col] = 1.0f / (1.0f + expf(-g));
            }
        }
    }
    __syncthreads();

    // ---- in-block gating top-k: wave wv handles tokens [wv*8, wv*8+8)
    const float4 bv = ((const float4*)bias)[lane];
    for (int tt = 0; tt < 8; ++tt) {
        const int lt = wv * 8 + tt;          // local token
        const int t  = tok0 + lt;            // global token
        f32x4 sv = *(const f32x4*)&sigbuf[lt * NEXP + lane * 4];
        const float sig0 = sv.x, sig1 = sv.y, sig2 = sv.z, sig3 = sv.w;
        const float sc0 = sig0 + bv.x, sc1 = sig1 + bv.y;
        const float sc2 = sig2 + bv.z, sc3 = sig3 + bv.w;

        // top-2 of my 4 scores
        float m1 = fmaxf(sc0, sc1);
        float m2 = fminf(sc0, sc1);
        if (sc2 > m1) { m2 = m1; m1 = sc2; } else m2 = fmaxf(m2, sc2);
        if (sc3 > m1) { m2 = m1; m1 = sc3; } else m2 = fmaxf(m2, sc3);
        // merge across the 8 lanes of this group (group = lane>>3, 32 experts)
        #pragma unroll
        for (int off = 1; off < 8; off <<= 1) {
            float o1 = __shfl_xor(m1, off);
            float o2 = __shfl_xor(m2, off);
            float nm1 = fmaxf(m1, o1);
            float nm2 = fmaxf(fminf(m1, o1), fmaxf(m2, o2));
            m1 = nm1; m2 = nm2;
        }
        float gsum = m1 + m2;
        float gs[8];
        #pragma unroll
        for (int gi = 0; gi < 8; ++gi) gs[gi] = __shfl(gsum, gi * 8);

        // keep the KDROP smallest groups (tie -> lower index), faithful to ref
        int keepmask = 0;
        #pragma unroll
        for (int g = 0; g < 8; ++g) {
            int rank = 0;
            #pragma unroll
            for (int h = 0; h < 8; ++h)
                rank += (gs[h] < gs[g]) || (gs[h] == gs[g] && h < g);
            if (rank < KDROP) keepmask |= (1 << g);
        }
        const bool kept = (keepmask >> (lane >> 3)) & 1;

        // lexicographic (value asc, index asc) keys; masked entries = +0.0
        const unsigned ib = (unsigned)(lane * 4);
        unsigned long long k0 = ((unsigned long long)ordkey(kept ? sc0 : 0.0f) << 32) | (ib + 0);
        unsigned long long k1 = ((unsigned long long)ordkey(kept ? sc1 : 0.0f) << 32) | (ib + 1);
        unsigned long long k2 = ((unsigned long long)ordkey(kept ? sc2 : 0.0f) << 32) | (ib + 2);
        unsigned long long k3 = ((unsigned long long)ordkey(kept ? sc3 : 0.0f) << 32) | (ib + 3);

        float ssum = 0.0f, myval = 0.0f;
        int myidx = 0;
        #pragma unroll
        for (int r = 0; r < TOPK; ++r) {
            unsigned long long kmin = k0 < k1 ? k0 : k1;
            if (k2 < kmin) kmin = k2;
            if (k3 < kmin) kmin = k3;
            #pragma unroll
            for (int off = 32; off >= 1; off >>= 1) {
                unsigned long long o = __shfl_xor(kmin, off);
                if (o < kmin) kmin = o;
            }
            const int id   = (int)(kmin & 0xffffffffull);
            const int src  = id >> 2;   // owning lane (wave-uniform)
            const int slot = id & 3;    // wave-uniform
            float vsrc = (slot == 0) ? sig0 : (slot == 1) ? sig1
                       : (slot == 2) ? sig2 : sig3;
            float v = __shfl(vsrc, src);
            ssum += v;
            if (lane == r) { myidx = id; myval = v; }
            const bool mine = (lane == src);
            if (mine && slot == 0) k0 = ~0ull;
            if (mine && slot == 1) k1 = ~0ull;
            if (mine && slot == 2) k2 = ~0ull;
            if (mine && slot == 3) k3 = ~0ull;
        }

        if (lane < TOPK) {
            out[(size_t)t * TOPK + lane] = (float)myidx;                      // inds
            out[(size_t)TOKENS * TOPK + (size_t)t * TOPK + lane] =
                myval / (ssum + 1e-20f) * 2.5f;                               // sel
        }
    }
}

// ---------------------------------------------------------------------------
extern "C" void kernel_launch(void* const* d_in, const int* in_sizes, int n_in,
                              void* d_out, int out_size, void* d_ws, size_t ws_size,
                              hipStream_t stream)
{
    const float* x    = (const float*)d_in[0];
    const float* w    = (const float*)d_in[1];
    const float* bias = (const float*)d_in[2];
    float* out = (float*)d_out;

    _Float16*  wh = (_Float16*)((char*)d_ws + WS_WH_OFF);
    _Float16*  wl = (_Float16*)((char*)d_ws + WS_WL_OFF);

    // split w into chunk-ordered f16 hi/lo
    wsplit<<<dim3(512), dim3(256), 0, stream>>>(w, wh, wl);
    // fused full-K split-f16 MFMA GEMM + sigmoid + in-block top-k
    gemm_gate<<<dim3(TOKENS / 32), dim3(256), 0, stream>>>(x, wh, wl, bias, out);
}